// Round 6
// baseline (4319.045 us; speedup 1.0000x reference)
//
#include <hip/hip_runtime.h>
#include <hip/hip_fp16.h>

typedef _Float16 f16;
typedef __attribute__((ext_vector_type(8))) _Float16 f16x8;
typedef __attribute__((ext_vector_type(16))) float f32x16;
typedef __attribute__((ext_vector_type(2))) unsigned long long u64x2;
typedef unsigned long long u64;

#define NB 2048      // batch
#define SEQ 64       // warmup sequence length
#define NF 3         // features
#define NU 512       // units
#define N4U 2048     // 4*units
#define NSTEP 127    // 64 warmup + 63 rollout
#define WT_LD 520    // 512 + 8 fp16 pad (65 16B-granules/row -> conflict-free b128)

#define SM_WT_BYTES (128 * WT_LD * 2)          // 133120 B: W^T slice, fp16
#define SM_XS_OFF   SM_WT_BYTES                // x stage: float[128*3]
#define SM_TOTAL    (SM_XS_OFF + 128 * 3 * 4)  // 134656 B

// ws layout
#define WS_PP_OFF   (16 * 1024)                // pred partials after flag area
#define WS_H_OFF    (1u << 20)                 // h double buffer: 2 x 2 MB fp16
#define PP_PAR_STRIDE (16 * 16 * 128 * 3)      // floats per parity buffer (98304)
#define PP_BT_STRIDE  (16 * 128 * 3)
#define PP_UG_STRIDE  (128 * 3)

__device__ __forceinline__ float fast_rcp(float x) { return __builtin_amdgcn_rcpf(x); }
__device__ __forceinline__ float sigf(float x) { return fast_rcp(1.f + __expf(-x)); }
__device__ __forceinline__ float tanhf_fast(float x) {
    float a = fabsf(x);
    float e = __expf(-2.f * a);
    float t = (1.f - e) * fast_rcp(1.f + e);
    return copysignf(t, x);
}

// Agent-scope h store (R3-proven): sc1 short store, IF-coherent, no cache maintenance.
__device__ __forceinline__ void st_h16_sc1(f16* p, f16 v) {
    unsigned b = (unsigned)__builtin_bit_cast(unsigned short, v);
    asm volatile("global_store_short %0, %1, off sc1" :: "v"(p), "v"(b) : "memory");
}

__global__ __launch_bounds__(256, 1)
void lstm_feedback_kernel(const float* __restrict__ inputs, const float* __restrict__ kernw,
                          const float* __restrict__ rec, const float* __restrict__ bias,
                          const float* __restrict__ dw, const float* __restrict__ db,
                          float* __restrict__ out, float* __restrict__ pp,
                          f16* __restrict__ hbuf, unsigned* __restrict__ flags)
{
    extern __shared__ char smem[];
    f16* Wt = (f16*)smem;                         // [128 cols][WT_LD k] fp16
    float* x_s = (float*)(smem + SM_XS_OFF);      // [128][3]

    const int tid = threadIdx.x;
    const int bid = blockIdx.x;
    // Swizzle so the 16 blocks of one bt share bid%8 (same XCD under round-robin) —
    // perf heuristic only; correctness is sc1/agent-scope and placement-independent.
    const int xcd = bid & 7;
    const int jj  = bid >> 3;
    const int bt  = (xcd << 1) | (jj & 1);   // b-tile 0..15 (the sync domain)
    const int ug  = jj >> 1;                 // u-group 0..15
    const int uBase = ug * 32;
    const int bBase = bt * 128;
    const int w  = tid >> 6;          // wave 0..3 (splits b)
    const int l  = tid & 63;
    const int l31 = l & 31;
    const int hf  = l >> 5;           // half-wave
    unsigned* myflags = flags + bt * 32;  // 16 dwords used, 128B stride per bt

    // ---- stage W^T slice into LDS as fp16 (cols = 4 gates x 32 u), once
    {
        const int c  = tid & 127;
        const int kk = tid >> 7;
        const int gcol = ((c >> 5) * 512) + uBase + (c & 31);
        for (int k = kk; k < NU; k += 2)
            Wt[c * WT_LD + k] = (f16)rec[k * N4U + gcol];
    }

    // ---- per-lane constants
    float kr[4][3], br[4], dwr[3], dbr[3];
    #pragma unroll
    for (int ct = 0; ct < 4; ++ct) {
        const int gcol = ct * 512 + uBase + l31;
        #pragma unroll
        for (int f = 0; f < 3; ++f) kr[ct][f] = kernw[f * N4U + gcol];
        br[ct] = bias[gcol];
    }
    {
        const int u = uBase + l31;
        #pragma unroll
        for (int j = 0; j < 3; ++j) { dwr[j] = dw[u * 3 + j]; dbr[j] = db[j]; }
    }
    __syncthreads();

    float c_reg[16];
    #pragma unroll
    for (int r = 0; r < 16; ++r) c_reg[r] = 0.f;

    const size_t HB = (size_t)NB * NU;
    const int bW = bBase + w * 32;
    const size_t aoff = (size_t)(bW + l31) * NU + hf * 8;   // f16 offset of lane's A row
    const f16* bptr = Wt + (size_t)l31 * WT_LD + hf * 8;

    for (int s = 0; s < NSTEP; ++s) {
        // ---- acquire: wait for the 16 peer flags (sc1 atomic loads — no cache inv needed)
        if (s > 0) {
            if (tid < 16) {
                const unsigned* fp = myflags + tid;
                unsigned v;
                do {
                    v = __hip_atomic_load(fp, __ATOMIC_RELAXED, __HIP_MEMORY_SCOPE_AGENT);
                } while (v < (unsigned)s);
            }
            __syncthreads();
        }

        // ---- prefetch ALL A-fragments via agent-scope (sc1) u64 loads — 64 parallel
        //      loads, compiler-tracked waits; one IF round-trip for the whole tile.
        u64 hA[64];
        if (s > 0) {
            const u64* ldp = (const u64*)(hbuf + (size_t)(s & 1) * HB + aoff);
            #pragma unroll
            for (int kt = 0; kt < 32; ++kt) {
                hA[2 * kt]     = __hip_atomic_load(ldp + kt * 4,
                                     __ATOMIC_RELAXED, __HIP_MEMORY_SCOPE_AGENT);
                hA[2 * kt + 1] = __hip_atomic_load(ldp + kt * 4 + 1,
                                     __ATOMIC_RELAXED, __HIP_MEMORY_SCOPE_AGENT);
            }
        }

        // ---- stage x (warmup: inputs[:,s,:] plain; rollout: pp via sc1 atomic loads)
        if (tid < 128) {
            float v0, v1, v2;
            if (s < SEQ) {
                const float* xp = inputs + ((size_t)(bBase + tid) * SEQ + s) * NF;
                v0 = xp[0]; v1 = xp[1]; v2 = xp[2];
            } else {
                const float* p = pp + (size_t)((s + 1) & 1) * PP_PAR_STRIDE
                               + bt * PP_BT_STRIDE + tid * 3;
                v0 = dbr[0]; v1 = dbr[1]; v2 = dbr[2];
                #pragma unroll
                for (int g = 0; g < 16; ++g) {
                    v0 += __hip_atomic_load(p + g * PP_UG_STRIDE + 0,
                             __ATOMIC_RELAXED, __HIP_MEMORY_SCOPE_AGENT);
                    v1 += __hip_atomic_load(p + g * PP_UG_STRIDE + 1,
                             __ATOMIC_RELAXED, __HIP_MEMORY_SCOPE_AGENT);
                    v2 += __hip_atomic_load(p + g * PP_UG_STRIDE + 2,
                             __ATOMIC_RELAXED, __HIP_MEMORY_SCOPE_AGENT);
                }
                if (ug == 0) {  // final output: each pred element stored exactly once
                    float* o = out + ((size_t)(s - SEQ) * NB + bBase + tid) * 3;
                    o[0] = v0; o[1] = v1; o[2] = v2;
                }
            }
            x_s[tid * 3 + 0] = v0;
            x_s[tid * 3 + 1] = v1;
            x_s[tid * 3 + 2] = v2;
        }
        __syncthreads();

        f32x16 acc0 = {}, acc1 = {}, acc2 = {}, acc3 = {};
        if (s > 0) {
            #pragma unroll 8
            for (int kt = 0; kt < 32; ++kt) {
                const int k0 = kt * 16;
                u64x2 t; t.x = hA[2 * kt]; t.y = hA[2 * kt + 1];
                f16x8 a  = __builtin_bit_cast(f16x8, t);
                f16x8 b0 = *(const f16x8*)(bptr + 0 * 32 * WT_LD + k0);
                f16x8 b1 = *(const f16x8*)(bptr + 1 * 32 * WT_LD + k0);
                f16x8 b2 = *(const f16x8*)(bptr + 2 * 32 * WT_LD + k0);
                f16x8 b3 = *(const f16x8*)(bptr + 3 * 32 * WT_LD + k0);
                acc0 = __builtin_amdgcn_mfma_f32_32x32x16_f16(a, b0, acc0, 0, 0, 0);
                acc1 = __builtin_amdgcn_mfma_f32_32x32x16_f16(a, b1, acc1, 0, 0, 0);
                acc2 = __builtin_amdgcn_mfma_f32_32x32x16_f16(a, b2, acc2, 0, 0, 0);
                acc3 = __builtin_amdgcn_mfma_f32_32x32x16_f16(a, b3, acc3, 0, 0, 0);
            }
        }

        // ---- gates + state update + sc1 h/pp stores
        f16* hw = hbuf + (size_t)((s & 1) ^ 1) * HB;
        const int n_out = s - (SEQ - 1);
        float* ppw = pp + (size_t)(s & 1) * PP_PAR_STRIDE
                   + bt * PP_BT_STRIDE + ug * PP_UG_STRIDE;
        #pragma unroll
        for (int r = 0; r < 16; ++r) {
            const int mrow = (r & 3) + ((r >> 2) << 3) + (hf << 2);
            const int mloc = (w << 5) + mrow;
            const float x0 = x_s[mloc * 3 + 0];
            const float x1 = x_s[mloc * 3 + 1];
            const float x2 = x_s[mloc * 3 + 2];
            float z0 = acc0[r] + x0 * kr[0][0] + x1 * kr[0][1] + x2 * kr[0][2] + br[0];
            float z1 = acc1[r] + x0 * kr[1][0] + x1 * kr[1][1] + x2 * kr[1][2] + br[1];
            float z2 = acc2[r] + x0 * kr[2][0] + x1 * kr[2][1] + x2 * kr[2][2] + br[2];
            float z3 = acc3[r] + x0 * kr[3][0] + x1 * kr[3][1] + x2 * kr[3][2] + br[3];
            const float gi = sigf(z0);
            const float gf = sigf(z1);
            const float gg = tanhf_fast(z2);
            const float go = sigf(z3);
            const float cv = gf * c_reg[r] + gi * gg;
            c_reg[r] = cv;
            const float h2 = go * tanhf_fast(cv);
            st_h16_sc1(hw + (size_t)(bBase + mloc) * NU + uBase + l31, (f16)h2);

            if (n_out >= 0) {
                #pragma unroll
                for (int j = 0; j < 3; ++j) {
                    float v = h2 * dwr[j];
                    #pragma unroll
                    for (int m = 1; m < 32; m <<= 1) v += __shfl_xor(v, m, 64);
                    if (l31 == r)
                        __hip_atomic_store(&ppw[mloc * 3 + j], v,
                                           __ATOMIC_RELAXED, __HIP_MEMORY_SCOPE_AGENT);
                }
            }
        }

        // ---- release: __syncthreads drains every wave's sc1 stores (vmcnt(0) before
        //      s_barrier), then one sc1 flag store publishes the step.
        __syncthreads();
        if (tid == 0)
            __hip_atomic_store(myflags + ug, (unsigned)(s + 1),
                               __ATOMIC_RELAXED, __HIP_MEMORY_SCOPE_AGENT);
    }

    // ---- epilogue: pred slot 63 (partials from step 126, parity 0)
    if (ug == 0) {
        if (tid < 16) {
            const unsigned* fp = myflags + tid;
            unsigned v;
            do {
                v = __hip_atomic_load(fp, __ATOMIC_RELAXED, __HIP_MEMORY_SCOPE_AGENT);
            } while (v < (unsigned)NSTEP);
        }
        __syncthreads();
        if (tid < 128) {
            const float* p = pp + bt * PP_BT_STRIDE + tid * 3;   // parity 0
            float v0 = dbr[0], v1 = dbr[1], v2 = dbr[2];
            #pragma unroll
            for (int g = 0; g < 16; ++g) {
                v0 += __hip_atomic_load(p + g * PP_UG_STRIDE + 0,
                         __ATOMIC_RELAXED, __HIP_MEMORY_SCOPE_AGENT);
                v1 += __hip_atomic_load(p + g * PP_UG_STRIDE + 1,
                         __ATOMIC_RELAXED, __HIP_MEMORY_SCOPE_AGENT);
                v2 += __hip_atomic_load(p + g * PP_UG_STRIDE + 2,
                         __ATOMIC_RELAXED, __HIP_MEMORY_SCOPE_AGENT);
            }
            float* o = out + ((size_t)63 * NB + bBase + tid) * 3;
            o[0] = v0; o[1] = v1; o[2] = v2;
        }
    }
}

extern "C" void kernel_launch(void* const* d_in, const int* in_sizes, int n_in,
                              void* d_out, int out_size, void* d_ws, size_t ws_size,
                              hipStream_t stream) {
    const float* inputs = (const float*)d_in[0];
    const float* kernw  = (const float*)d_in[1];
    const float* rec    = (const float*)d_in[2];
    const float* bias   = (const float*)d_in[3];
    const float* dw     = (const float*)d_in[4];
    const float* db     = (const float*)d_in[5];
    float* out = (float*)d_out;

    unsigned* flags = (unsigned*)d_ws;                       // 16 x 128B flag lines
    float* pp  = (float*)((char*)d_ws + WS_PP_OFF);          // pred partials, 2 parities
    f16* hbuf  = (f16*)((char*)d_ws + WS_H_OFF);             // double-buffered h: 2 x 2 MB

    hipMemsetAsync(d_ws, 0, 16 * 1024, stream);              // zero flags

    hipFuncSetAttribute(reinterpret_cast<const void*>(lstm_feedback_kernel),
                        hipFuncAttributeMaxDynamicSharedMemorySize, SM_TOTAL);

    void* args[] = { (void*)&inputs, (void*)&kernw, (void*)&rec, (void*)&bias,
                     (void*)&dw, (void*)&db, (void*)&out, (void*)&pp,
                     (void*)&hbuf, (void*)&flags };
    hipLaunchCooperativeKernel(reinterpret_cast<const void*>(lstm_feedback_kernel),
                               dim3(256), dim3(256), args, SM_TOTAL, stream);
}

// Round 8
// 4187.633 us; speedup vs baseline: 1.0314x; 1.0314x over previous
//
#include <hip/hip_runtime.h>
#include <hip/hip_fp16.h>

typedef _Float16 f16;
typedef __attribute__((ext_vector_type(8))) _Float16 f16x8;
typedef __attribute__((ext_vector_type(16))) float f32x16;
typedef __attribute__((ext_vector_type(2))) unsigned long long u64x2;
typedef unsigned long long u64;

#define NB 2048      // batch
#define SEQ 64       // warmup sequence length
#define NF 3         // features
#define NU 512       // units
#define N4U 2048     // 4*units
#define NSTEP 127    // 64 warmup + 63 rollout
#define WT_LD 520    // 512 + 8 fp16 pad (65 16B-granules/row -> conflict-free b128)

#define SM_WT_BYTES (128 * WT_LD * 2)          // 133120 B: W^T slice, fp16
#define SM_XS_OFF   SM_WT_BYTES                // x stage: float[128*3] = 1536 B
#define SM_HS_OFF   (SM_XS_OFF + 1536)         // h-out stage: 128*32 fp16 = 8192 B
#define SM_PS_OFF   (SM_HS_OFF + 8192)         // pred stage: float[128*3] = 1536 B
#define SM_TOTAL    (SM_PS_OFF + 1536)         // 144384 B (< 160 KiB)

// ws layout
#define WS_PP_OFF   (16 * 1024)                // pred partials after flag area
#define WS_H_OFF    (1u << 20)                 // h double buffer: 2 x 2 MB fp16
#define PP_PAR_STRIDE (16 * 16 * 128 * 3)      // floats per parity buffer (98304)
#define PP_BT_STRIDE  (16 * 128 * 3)
#define PP_UG_STRIDE  (128 * 3)                // 1536 B per (bt,ug) slice

__device__ __forceinline__ float fast_rcp(float x) { return __builtin_amdgcn_rcpf(x); }
__device__ __forceinline__ float sigf(float x) { return fast_rcp(1.f + __expf(-x)); }
__device__ __forceinline__ float tanhf_fast(float x) {
    float a = fabsf(x);
    float e = __expf(-2.f * a);
    float t = (1.f - e) * fast_rcp(1.f + e);
    return copysignf(t, x);
}

__global__ __launch_bounds__(256, 1)
void lstm_feedback_kernel(const float* __restrict__ inputs, const float* __restrict__ kernw,
                          const float* __restrict__ rec, const float* __restrict__ bias,
                          const float* __restrict__ dw, const float* __restrict__ db,
                          float* __restrict__ out, float* __restrict__ pp,
                          f16* __restrict__ hbuf, unsigned* __restrict__ flags)
{
    extern __shared__ char smem[];
    f16* Wt = (f16*)smem;                         // [128 cols][WT_LD k] fp16
    float* x_s = (float*)(smem + SM_XS_OFF);      // [128][3]
    f16* hst = (f16*)(smem + SM_HS_OFF);          // [128 rows][32 cols] h-out stage
    float* ps = (float*)(smem + SM_PS_OFF);       // [128][3] pred-partial stage

    const int tid = threadIdx.x;
    const int bid = blockIdx.x;
    // Swizzle so the 16 blocks of one bt share bid%8 (same XCD under round-robin) —
    // perf heuristic only; correctness is sc1/agent-scope and placement-independent.
    const int xcd = bid & 7;
    const int jj  = bid >> 3;
    const int bt  = (xcd << 1) | (jj & 1);   // b-tile 0..15 (the sync domain)
    const int ug  = jj >> 1;                 // u-group 0..15
    const int uBase = ug * 32;
    const int bBase = bt * 128;
    const int w  = tid >> 6;          // wave 0..3 (splits b)
    const int l  = tid & 63;
    const int l31 = l & 31;
    const int hf  = l >> 5;           // half-wave
    unsigned* myflags = flags + bt * 32;  // 16 dwords used, 128B stride per bt

    // ---- stage W^T slice into LDS as fp16 (cols = 4 gates x 32 u), once
    {
        const int c  = tid & 127;
        const int kk = tid >> 7;
        const int gcol = ((c >> 5) * 512) + uBase + (c & 31);
        for (int k = kk; k < NU; k += 2)
            Wt[c * WT_LD + k] = (f16)rec[k * N4U + gcol];
    }

    // ---- per-lane constants
    float kr[4][3], br[4], dwr[3], dbr[3];
    #pragma unroll
    for (int ct = 0; ct < 4; ++ct) {
        const int gcol = ct * 512 + uBase + l31;
        #pragma unroll
        for (int f = 0; f < 3; ++f) kr[ct][f] = kernw[f * N4U + gcol];
        br[ct] = bias[gcol];
    }
    {
        const int u = uBase + l31;
        #pragma unroll
        for (int j = 0; j < 3; ++j) { dwr[j] = dw[u * 3 + j]; dbr[j] = db[j]; }
    }
    __syncthreads();

    float c_reg[16];
    #pragma unroll
    for (int r = 0; r < 16; ++r) c_reg[r] = 0.f;

    const size_t HB = (size_t)NB * NU;
    const int bW = bBase + w * 32;
    const size_t aoff = (size_t)(bW + l31) * NU + hf * 8;   // f16 offset of lane's A row
    const f16* bptr = Wt + (size_t)l31 * WT_LD + hf * 8;
    // coalesced h-out geometry: 8 lanes cover one row's 64B slice (8B per lane)
    const int srow8 = l >> 3;             // 0..7
    const int scol4 = (l & 7) * 4;        // f16 col offset (4 f16 = 8B per lane)

    for (int s = 0; s < NSTEP; ++s) {
        // ---- acquire: wait for the 16 peer flags (sc1 atomic loads)
        if (s > 0) {
            if (tid < 16) {
                const unsigned* fp = myflags + tid;
                unsigned v;
                do {
                    v = __hip_atomic_load(fp, __ATOMIC_RELAXED, __HIP_MEMORY_SCOPE_AGENT);
                } while (v < (unsigned)s);
            }
            __syncthreads();
        }

        // ---- stage x FIRST (its pp round-trip overlaps nothing behind it)
        if (tid < 128) {
            float v0, v1, v2;
            if (s < SEQ) {
                const float* xp = inputs + ((size_t)(bBase + tid) * SEQ + s) * NF;
                v0 = xp[0]; v1 = xp[1]; v2 = xp[2];
            } else {
                const float* p = pp + (size_t)((s + 1) & 1) * PP_PAR_STRIDE
                               + bt * PP_BT_STRIDE + tid * 3;
                v0 = dbr[0]; v1 = dbr[1]; v2 = dbr[2];
                #pragma unroll
                for (int g = 0; g < 16; ++g) {
                    v0 += __hip_atomic_load(p + g * PP_UG_STRIDE + 0,
                             __ATOMIC_RELAXED, __HIP_MEMORY_SCOPE_AGENT);
                    v1 += __hip_atomic_load(p + g * PP_UG_STRIDE + 1,
                             __ATOMIC_RELAXED, __HIP_MEMORY_SCOPE_AGENT);
                    v2 += __hip_atomic_load(p + g * PP_UG_STRIDE + 2,
                             __ATOMIC_RELAXED, __HIP_MEMORY_SCOPE_AGENT);
                }
                if (ug == 0) {  // final output: each pred element stored exactly once
                    float* o = out + ((size_t)(s - SEQ) * NB + bBase + tid) * 3;
                    o[0] = v0; o[1] = v1; o[2] = v2;
                }
            }
            x_s[tid * 3 + 0] = v0;
            x_s[tid * 3 + 1] = v1;
            x_s[tid * 3 + 2] = v2;
        }

        // ---- A prefetch: 64 tracked sc1 u64 loads, batched; land at the barrier below
        u64 hA[64];
        if (s > 0) {
            const u64* ldp = (const u64*)(hbuf + (size_t)(s & 1) * HB + aoff);
            #pragma unroll
            for (int kt = 0; kt < 32; ++kt) {
                hA[2 * kt]     = __hip_atomic_load(ldp + kt * 4,
                                     __ATOMIC_RELAXED, __HIP_MEMORY_SCOPE_AGENT);
                hA[2 * kt + 1] = __hip_atomic_load(ldp + kt * 4 + 1,
                                     __ATOMIC_RELAXED, __HIP_MEMORY_SCOPE_AGENT);
            }
            __builtin_amdgcn_sched_barrier(0);   // keep the batch together
        }
        __syncthreads();   // x_s ready; vmcnt(0) here = single landing point for hA

        f32x16 acc0 = {}, acc1 = {}, acc2 = {}, acc3 = {};
        if (s > 0) {
            #pragma unroll 8
            for (int kt = 0; kt < 32; ++kt) {
                const int k0 = kt * 16;
                u64x2 t; t.x = hA[2 * kt]; t.y = hA[2 * kt + 1];
                f16x8 a  = __builtin_bit_cast(f16x8, t);
                f16x8 b0 = *(const f16x8*)(bptr + 0 * 32 * WT_LD + k0);
                f16x8 b1 = *(const f16x8*)(bptr + 1 * 32 * WT_LD + k0);
                f16x8 b2 = *(const f16x8*)(bptr + 2 * 32 * WT_LD + k0);
                f16x8 b3 = *(const f16x8*)(bptr + 3 * 32 * WT_LD + k0);
                acc0 = __builtin_amdgcn_mfma_f32_32x32x16_f16(a, b0, acc0, 0, 0, 0);
                acc1 = __builtin_amdgcn_mfma_f32_32x32x16_f16(a, b1, acc1, 0, 0, 0);
                acc2 = __builtin_amdgcn_mfma_f32_32x32x16_f16(a, b2, acc2, 0, 0, 0);
                acc3 = __builtin_amdgcn_mfma_f32_32x32x16_f16(a, b3, acc3, 0, 0, 0);
            }
        }

        // ---- gates + state update; h2 and pred partials staged in LDS
        const int n_out = s - (SEQ - 1);
        #pragma unroll
        for (int r = 0; r < 16; ++r) {
            const int mrow = (r & 3) + ((r >> 2) << 3) + (hf << 2);
            const int mloc = (w << 5) + mrow;
            const float x0 = x_s[mloc * 3 + 0];
            const float x1 = x_s[mloc * 3 + 1];
            const float x2 = x_s[mloc * 3 + 2];
            float z0 = acc0[r] + x0 * kr[0][0] + x1 * kr[0][1] + x2 * kr[0][2] + br[0];
            float z1 = acc1[r] + x0 * kr[1][0] + x1 * kr[1][1] + x2 * kr[1][2] + br[1];
            float z2 = acc2[r] + x0 * kr[2][0] + x1 * kr[2][1] + x2 * kr[2][2] + br[2];
            float z3 = acc3[r] + x0 * kr[3][0] + x1 * kr[3][1] + x2 * kr[3][2] + br[3];
            const float gi = sigf(z0);
            const float gf = sigf(z1);
            const float gg = tanhf_fast(z2);
            const float go = sigf(z3);
            const float cv = gf * c_reg[r] + gi * gg;
            c_reg[r] = cv;
            const float h2 = go * tanhf_fast(cv);
            hst[mloc * 32 + l31] = (f16)h2;   // 2-way bank alias = free

            if (n_out >= 0) {
                #pragma unroll
                for (int j = 0; j < 3; ++j) {
                    float v = h2 * dwr[j];
                    #pragma unroll
                    for (int m = 1; m < 32; m <<= 1) v += __shfl_xor(v, m, 64);
                    if (l31 == r) ps[mloc * 3 + j] = v;
                }
            }
        }
        __syncthreads();   // hst + ps complete

        // ---- coalesced h-out: per wave 32 rows x 64B slices as contiguous u64 stores
        {
            f16* hw = hbuf + (size_t)((s & 1) ^ 1) * HB;
            #pragma unroll
            for (int j = 0; j < 4; ++j) {
                const int row = (w << 5) + (j << 3) + srow8;        // 0..127
                u64 v = *(const u64*)(hst + row * 32 + scol4);      // ds_read_b64
                __hip_atomic_store((u64*)(hw + (size_t)(bBase + row) * NU + uBase + scol4),
                                   v, __ATOMIC_RELAXED, __HIP_MEMORY_SCOPE_AGENT);
            }
        }

        // ---- coalesced pp-out: 1536B slice as 192 contiguous u64 stores
        if (n_out >= 0 && tid < 192) {
            float* ppw = pp + (size_t)(s & 1) * PP_PAR_STRIDE
                       + bt * PP_BT_STRIDE + ug * PP_UG_STRIDE;
            u64 v = *(const u64*)((const char*)ps + tid * 8);
            __hip_atomic_store((u64*)((char*)ppw + tid * 8), v,
                               __ATOMIC_RELAXED, __HIP_MEMORY_SCOPE_AGENT);
        }

        // ---- release: barrier drains every wave's stores (vmcnt(0)), publish flag
        __syncthreads();
        if (tid == 0)
            __hip_atomic_store(myflags + ug, (unsigned)(s + 1),
                               __ATOMIC_RELAXED, __HIP_MEMORY_SCOPE_AGENT);
    }

    // ---- epilogue: pred slot 63 (partials from step 126, parity 0)
    if (ug == 0) {
        if (tid < 16) {
            const unsigned* fp = myflags + tid;
            unsigned v;
            do {
                v = __hip_atomic_load(fp, __ATOMIC_RELAXED, __HIP_MEMORY_SCOPE_AGENT);
            } while (v < (unsigned)NSTEP);
        }
        __syncthreads();
        if (tid < 128) {
            const float* p = pp + bt * PP_BT_STRIDE + tid * 3;   // parity 0
            float v0 = dbr[0], v1 = dbr[1], v2 = dbr[2];
            #pragma unroll
            for (int g = 0; g < 16; ++g) {
                v0 += __hip_atomic_load(p + g * PP_UG_STRIDE + 0,
                         __ATOMIC_RELAXED, __HIP_MEMORY_SCOPE_AGENT);
                v1 += __hip_atomic_load(p + g * PP_UG_STRIDE + 1,
                         __ATOMIC_RELAXED, __HIP_MEMORY_SCOPE_AGENT);
                v2 += __hip_atomic_load(p + g * PP_UG_STRIDE + 2,
                         __ATOMIC_RELAXED, __HIP_MEMORY_SCOPE_AGENT);
            }
            float* o = out + ((size_t)63 * NB + bBase + tid) * 3;
            o[0] = v0; o[1] = v1; o[2] = v2;
        }
    }
}

extern "C" void kernel_launch(void* const* d_in, const int* in_sizes, int n_in,
                              void* d_out, int out_size, void* d_ws, size_t ws_size,
                              hipStream_t stream) {
    const float* inputs = (const float*)d_in[0];
    const float* kernw  = (const float*)d_in[1];
    const float* rec    = (const float*)d_in[2];
    const float* bias   = (const float*)d_in[3];
    const float* dw     = (const float*)d_in[4];
    const float* db     = (const float*)d_in[5];
    float* out = (float*)d_out;

    unsigned* flags = (unsigned*)d_ws;                       // 16 x 128B flag lines
    float* pp  = (float*)((char*)d_ws + WS_PP_OFF);          // pred partials, 2 parities
    f16* hbuf  = (f16*)((char*)d_ws + WS_H_OFF);             // double-buffered h: 2 x 2 MB

    hipMemsetAsync(d_ws, 0, 16 * 1024, stream);              // zero flags

    hipFuncSetAttribute(reinterpret_cast<const void*>(lstm_feedback_kernel),
                        hipFuncAttributeMaxDynamicSharedMemorySize, SM_TOTAL);

    void* args[] = { (void*)&inputs, (void*)&kernw, (void*)&rec, (void*)&bias,
                     (void*)&dw, (void*)&db, (void*)&out, (void*)&pp,
                     (void*)&hbuf, (void*)&flags };
    hipLaunchCooperativeKernel(reinterpret_cast<const void*>(lstm_feedback_kernel),
                               dim3(256), dim3(256), args, SM_TOTAL, stream);
}